// Round 7
// baseline (210.296 us; speedup 1.0000x reference)
//
#include <hip/hip_runtime.h>

#define IMG 224
#define PATCHSZ 16
#define CHN 3
#define DDIM 768
#define ROWN 14
#define NPATCH 196
#define PDIM 768
#define BATCH 32

#define DTILE 256                 // d-cols per block (3 blocks per patch)
#define NDBLK (DDIM / DTILE)      // 3
#define KCHUNK 64                 // P chunk rows
#define NCHUNK (PDIM / KCHUNK)    // 12
#define KSUB 16                   // W subchunk rows
#define NSUB (PDIM / KSUB)        // 48

// Kernel 1: x[32][3][224][224] -> P[196][32][768]
__global__ void extract_patches_kernel(const float* __restrict__ x,
                                       float* __restrict__ P) {
    int i = blockIdx.x * blockDim.x + threadIdx.x;
    if (i >= NPATCH * BATCH * PDIM) return;
    int k  = i % PDIM;
    int nb = i / PDIM;
    int b  = nb % BATCH;
    int n  = nb / BATCH;
    int ch = k >> 8;
    int py = (k >> 4) & 15;
    int px = k & 15;
    int r = n / ROWN, c = n % ROWN;
    P[i] = x[(((size_t)b * CHN + ch) * IMG + r * PATCHSZ + py) * IMG
             + c * PATCHSZ + px];
}

#define ACC_ROW(i, pv, wj)                                                   \
    acc[i][0] = fmaf(pv, wj.x, acc[i][0]);                                   \
    acc[i][1] = fmaf(pv, wj.y, acc[i][1]);                                   \
    acc[i][2] = fmaf(pv, wj.z, acc[i][2]);                                   \
    acc[i][3] = fmaf(pv, wj.w, acc[i][3]);

// per patch n: out[:,n,d0:d0+256] = P[n] (32x768) * W[n][:,d0:d0+256] + bias
// grid 196*3, block 256; thread tile 8 batches x 4 d-cols.
// W: global_load_lds, 3-deep ring, COUNTED vmcnt (never drains to 0
// in the main loop) + raw s_barrier — the T3/T4 schedule.
__global__ __launch_bounds__(256, 2) void patch_gemm_kernel(
    const float* __restrict__ P,    // [196][32][768]
    const float* __restrict__ W,    // [196][768][768]
    const float* __restrict__ bias, // [196][768]
    float* __restrict__ out)        // [32][196][768]
{
    __shared__ __align__(16) float wt[3][KSUB][DTILE];   // 48 KB W ring
    __shared__ __align__(16) float ap[2][KCHUNK][BATCH]; // 16 KB P ping-pong

    const int blk  = blockIdx.x;
    const int n    = blk / NDBLK;
    const int dblk = blk % NDBLK;
    const int tid  = threadIdx.x;
    const int ln   = tid & 63;      // lane; d-quad index (64 x 4 = 256 cols)
    const int wv   = tid >> 6;      // wave 0..3
    const int b0   = wv * 8;        // batch group per wave
    const int d    = dblk * DTILE + ln * 4;

    const float* Wn0 = W + (size_t)n * PDIM * DDIM + dblk * DTILE;
    const float* Pn  = P + (size_t)n * BATCH * PDIM;

    // P staging mapping: thread -> (batch sb, 8 consecutive k at sk)
    const int sb = tid >> 3;          // 0..31
    const int sk = (tid & 7) * 8;     // 0..56

    float acc[8][4];
#pragma unroll
    for (int i = 0; i < 8; ++i)
#pragma unroll
        for (int j = 0; j < 4; ++j) acc[i][j] = 0.f;

    // issue one W subchunk (16 rows x 256 cols, 16 KB) into ring slot `slot`.
    // per wave: 4 x global_load_lds_dwordx4, one 1KB row each.
    auto issueW = [&](int u, int slot) {
        const float* src = Wn0 + (size_t)u * KSUB * DDIM;
        float* dst = &wt[slot][0][0];
#pragma unroll
        for (int j = 0; j < 4; ++j) {
            const int row = wv * 4 + j;
            __builtin_amdgcn_global_load_lds(
                (const __attribute__((address_space(1))) unsigned int*)
                    (src + (size_t)row * DDIM + ln * 4),
                (__attribute__((address_space(3))) unsigned int*)
                    (dst + row * DTILE + ln * 4),
                16, 0, 0);
        }
    };

    // prologue: stage P chunk 0 into ap[0] (completes before first barrier
    // via lgkmcnt(0)); issue W(0), W(1).
    {
        const float* s = Pn + (size_t)sb * PDIM + sk;
        float4 v0 = *reinterpret_cast<const float4*>(s);
        float4 v1 = *reinterpret_cast<const float4*>(s + 4);
        float (*apb)[BATCH] = ap[0];
        apb[sk + 0][sb] = v0.x; apb[sk + 1][sb] = v0.y;
        apb[sk + 2][sb] = v0.z; apb[sk + 3][sb] = v0.w;
        apb[sk + 4][sb] = v1.x; apb[sk + 5][sb] = v1.y;
        apb[sk + 6][sb] = v1.z; apb[sk + 7][sb] = v1.w;
    }
    issueW(0, 0);
    issueW(1, 1);

    float4 pn0, pn1;   // single P prefetch buffer: written @4c, read @4c+3
    int rd = 0;        // ring slot = v % 3

#pragma unroll 1
    for (int v = 0; v < NSUB; ++v) {
        // make P ds_writes (prev step) visible, then wait for W(v) only:
        // W(v+1)'s 4 loads (and possibly 2 pn loads) stay in flight.
        asm volatile("s_waitcnt lgkmcnt(0)" ::: "memory");
        if (v == NSUB - 1) {
            asm volatile("s_waitcnt vmcnt(0)" ::: "memory");
        } else {
            asm volatile("s_waitcnt vmcnt(4)" ::: "memory");
        }
        __builtin_amdgcn_s_barrier();

        // issue W(v+2) into slot (v+2)%3 — its last reader compute(v-1)
        // retired at the barrier above.
        int wr = rd + 2; if (wr >= 3) wr -= 3;
        if (v + 2 < NSUB) issueW(v + 2, wr);

        const int c  = v >> 2;          // P chunk index
        // prefetch P chunk c+1 at the first subchunk of chunk c
        if ((v & 3) == 0 && c + 1 < NCHUNK) {
            const float* s = Pn + (size_t)sb * PDIM + (c + 1) * KCHUNK + sk;
            pn0 = *reinterpret_cast<const float4*>(s);
            pn1 = *reinterpret_cast<const float4*>(s + 4);
        }

        const int kb = (v & 3) * KSUB;  // k offset within P chunk
        const float* wbuf = &wt[rd][0][0] + ln * 4;
        const float* pbuf = &ap[c & 1][0][0] + b0;

#pragma unroll 4
        for (int kk = 0; kk < KSUB; ++kk) {
            float4 w = *reinterpret_cast<const float4*>(wbuf + kk * DTILE);
            const float* pp = pbuf + (size_t)(kb + kk) * BATCH;
            float4 p01 = *reinterpret_cast<const float4*>(pp);
            float4 p23 = *reinterpret_cast<const float4*>(pp + 4);
            ACC_ROW(0, p01.x, w) ACC_ROW(1, p01.y, w)
            ACC_ROW(2, p01.z, w) ACC_ROW(3, p01.w, w)
            ACC_ROW(4, p23.x, w) ACC_ROW(5, p23.y, w)
            ACC_ROW(6, p23.z, w) ACC_ROW(7, p23.w, w)
        }

        // last subchunk of chunk c: publish P chunk c+1 (pn written @4c)
        if ((v & 3) == 3 && c + 1 < NCHUNK) {
            float (*apb)[BATCH] = ap[(c + 1) & 1];
            apb[sk + 0][sb] = pn0.x; apb[sk + 1][sb] = pn0.y;
            apb[sk + 2][sb] = pn0.z; apb[sk + 3][sb] = pn0.w;
            apb[sk + 4][sb] = pn1.x; apb[sk + 5][sb] = pn1.y;
            apb[sk + 6][sb] = pn1.z; apb[sk + 7][sb] = pn1.w;
        }

        rd = (rd == 2) ? 0 : rd + 1;
    }

    float4 bv = *reinterpret_cast<const float4*>(bias + (size_t)n * DDIM + d);
#pragma unroll
    for (int i = 0; i < 8; ++i) {
        const int b = b0 + i;
        float4 o;
        o.x = acc[i][0] + bv.x;
        o.y = acc[i][1] + bv.y;
        o.z = acc[i][2] + bv.z;
        o.w = acc[i][3] + bv.w;
        *reinterpret_cast<float4*>(out + ((size_t)b * NPATCH + n) * DDIM + d) = o;
    }
}

extern "C" void kernel_launch(void* const* d_in, const int* in_sizes, int n_in,
                              void* d_out, int out_size, void* d_ws, size_t ws_size,
                              hipStream_t stream) {
    const float* x    = (const float*)d_in[0];
    const float* W    = (const float*)d_in[1];
    const float* bias = (const float*)d_in[2];
    float* out = (float*)d_out;
    float* P   = (float*)d_ws;   // 196*32*768*4 = 19.3 MB

    int total = NPATCH * BATCH * PDIM;
    extract_patches_kernel<<<(total + 255) / 256, 256, 0, stream>>>(x, P);
    patch_gemm_kernel<<<NPATCH * NDBLK, 256, 0, stream>>>(P, W, bias, out);
}

// Round 8
// 165.726 us; speedup vs baseline: 1.2689x; 1.2689x over previous
//
#include <hip/hip_runtime.h>

#define IMG 224
#define PATCHSZ 16
#define CHN 3
#define DDIM 768
#define ROWN 14
#define NPATCH 196
#define PDIM 768
#define BATCH 32

#define DTILE 256                 // d-cols per block (3 blocks per patch)
#define NDBLK (DDIM / DTILE)      // 3
#define KCHUNK 64                 // P chunk rows
#define NCHUNK (PDIM / KCHUNK)    // 12
#define KSUB 16                   // W subchunk rows
#define NSUB (PDIM / KSUB)        // 48

// Kernel 1: x[32][3][224][224] -> P[196][32][768]
__global__ void extract_patches_kernel(const float* __restrict__ x,
                                       float* __restrict__ P) {
    int i = blockIdx.x * blockDim.x + threadIdx.x;
    if (i >= NPATCH * BATCH * PDIM) return;
    int k  = i % PDIM;
    int nb = i / PDIM;
    int b  = nb % BATCH;
    int n  = nb / BATCH;
    int ch = k >> 8;
    int py = (k >> 4) & 15;
    int px = k & 15;
    int r = n / ROWN, c = n % ROWN;
    P[i] = x[(((size_t)b * CHN + ch) * IMG + r * PATCHSZ + py) * IMG
             + c * PATCHSZ + px];
}

// packed fp32 FMA, P-value broadcast via op_sel (no mov):
// LO: both result halves use p.lo ; HI: both use p.hi
#define PK_FMA_LO(a2, w2, p2)                                                \
    asm("v_pk_fma_f32 %0, %1, %2, %0 op_sel:[0,0,0] op_sel_hi:[1,0,1]"       \
        : "+v"(a2) : "v"(w2), "v"(p2))
#define PK_FMA_HI(a2, w2, p2)                                                \
    asm("v_pk_fma_f32 %0, %1, %2, %0 op_sel:[0,1,0] op_sel_hi:[1,1,1]"       \
        : "+v"(a2) : "v"(w2), "v"(p2))

// per patch n: out[:,n,d0:d0+256] = P[n] (32x768) * W[n][:,d0:d0+256] + bias
// grid 196*3, block 256; thread tile 8 batches x 4 d-cols (as 8x2 float2).
// W: global_load_lds double-buffer (zero VGPR round trip). r4 structure.
__global__ __launch_bounds__(256, 2) void patch_gemm_kernel(
    const float* __restrict__ P,    // [196][32][768]
    const float* __restrict__ W,    // [196][768][768]
    const float* __restrict__ bias, // [196][768]
    float* __restrict__ out)        // [32][196][768]
{
    __shared__ __align__(16) float wt[2][KSUB][DTILE];   // 32 KB W ping-pong
    __shared__ __align__(16) float ap[2][KCHUNK][BATCH]; // 16 KB P ping-pong

    const int blk  = blockIdx.x;
    const int n    = blk / NDBLK;
    const int dblk = blk % NDBLK;
    const int tid  = threadIdx.x;
    const int ln   = tid & 63;      // lane; d-quad index (64 x 4 = 256 cols)
    const int wv   = tid >> 6;      // wave 0..3
    const int b0   = wv * 8;        // batch group per wave
    const int d    = dblk * DTILE + ln * 4;

    const float* Wn0 = W + (size_t)n * PDIM * DDIM + dblk * DTILE;
    const float* Pn  = P + (size_t)n * BATCH * PDIM;

    // P staging mapping: thread -> (batch sb, 8 consecutive k at sk)
    const int sb = tid >> 3;          // 0..31
    const int sk = (tid & 7) * 8;     // 0..56

    float2 acc[8][2];
#pragma unroll
    for (int i = 0; i < 8; ++i) {
        acc[i][0] = make_float2(0.f, 0.f);
        acc[i][1] = make_float2(0.f, 0.f);
    }

    // issue one W subchunk (16 rows x 256 cols, 16 KB) into wt[u&1].
    // per wave: 4 x global_load_lds_dwordx4, one 1KB row each.
    auto issueW = [&](int u) {
        const float* src = Wn0 + (size_t)u * KSUB * DDIM;
        float* dst = &wt[u & 1][0][0];
#pragma unroll
        for (int j = 0; j < 4; ++j) {
            const int row = wv * 4 + j;
            __builtin_amdgcn_global_load_lds(
                (const __attribute__((address_space(1))) unsigned int*)
                    (src + (size_t)row * DDIM + ln * 4),
                (__attribute__((address_space(3))) unsigned int*)
                    (dst + row * DTILE + ln * 4),
                16, 0, 0);
        }
    };

    // prologue: stage P chunk 0, prefetch P chunk 1, issue W subchunk 0
    {
        const float* s = Pn + (size_t)sb * PDIM + sk;
        float4 v0 = *reinterpret_cast<const float4*>(s);
        float4 v1 = *reinterpret_cast<const float4*>(s + 4);
        float (*apb)[BATCH] = ap[0];
        apb[sk + 0][sb] = v0.x; apb[sk + 1][sb] = v0.y;
        apb[sk + 2][sb] = v0.z; apb[sk + 3][sb] = v0.w;
        apb[sk + 4][sb] = v1.x; apb[sk + 5][sb] = v1.y;
        apb[sk + 6][sb] = v1.z; apb[sk + 7][sb] = v1.w;
    }
    float4 pn0, pn1;
    {
        const float* s = Pn + (size_t)sb * PDIM + KCHUNK + sk;
        pn0 = *reinterpret_cast<const float4*>(s);
        pn1 = *reinterpret_cast<const float4*>(s + 4);
    }
    issueW(0);

#pragma unroll 1
    for (int u = 0; u < NSUB; ++u) {
        __syncthreads();   // drains vmcnt+lgkmcnt: W(u) landed, P visible
        if (u + 1 < NSUB) issueW(u + 1);

        const int c  = u >> 2;          // P chunk index
        const int kb = (u & 3) * KSUB;  // k offset within P chunk
        const float* wbuf = &wt[u & 1][0][0] + ln * 4;
        const float* pbuf = &ap[c & 1][0][0] + b0;

#pragma unroll 4
        for (int kk = 0; kk < KSUB; ++kk) {
            const float* wp = wbuf + kk * DTILE;
            float2 wlo = *reinterpret_cast<const float2*>(wp);
            float2 whi = *reinterpret_cast<const float2*>(wp + 2);
            const float* pp = pbuf + (size_t)(kb + kk) * BATCH;
            // wave-uniform broadcast LDS reads (conflict-free)
            float2 p01 = *reinterpret_cast<const float2*>(pp);
            float2 p23 = *reinterpret_cast<const float2*>(pp + 2);
            float2 p45 = *reinterpret_cast<const float2*>(pp + 4);
            float2 p67 = *reinterpret_cast<const float2*>(pp + 6);

            PK_FMA_LO(acc[0][0], wlo, p01); PK_FMA_LO(acc[0][1], whi, p01);
            PK_FMA_HI(acc[1][0], wlo, p01); PK_FMA_HI(acc[1][1], whi, p01);
            PK_FMA_LO(acc[2][0], wlo, p23); PK_FMA_LO(acc[2][1], whi, p23);
            PK_FMA_HI(acc[3][0], wlo, p23); PK_FMA_HI(acc[3][1], whi, p23);
            PK_FMA_LO(acc[4][0], wlo, p45); PK_FMA_LO(acc[4][1], whi, p45);
            PK_FMA_HI(acc[5][0], wlo, p45); PK_FMA_HI(acc[5][1], whi, p45);
            PK_FMA_LO(acc[6][0], wlo, p67); PK_FMA_LO(acc[6][1], whi, p67);
            PK_FMA_HI(acc[7][0], wlo, p67); PK_FMA_HI(acc[7][1], whi, p67);
        }

        // at the last subchunk of chunk c: stage P chunk c+1, prefetch c+2
        if ((u & 3) == 3 && c + 1 < NCHUNK) {
            float (*apb)[BATCH] = ap[(c + 1) & 1];
            apb[sk + 0][sb] = pn0.x; apb[sk + 1][sb] = pn0.y;
            apb[sk + 2][sb] = pn0.z; apb[sk + 3][sb] = pn0.w;
            apb[sk + 4][sb] = pn1.x; apb[sk + 5][sb] = pn1.y;
            apb[sk + 6][sb] = pn1.z; apb[sk + 7][sb] = pn1.w;
            if (c + 2 < NCHUNK) {
                const float* s = Pn + (size_t)sb * PDIM + (c + 2) * KCHUNK + sk;
                pn0 = *reinterpret_cast<const float4*>(s);
                pn1 = *reinterpret_cast<const float4*>(s + 4);
            }
        }
    }

    float4 bv = *reinterpret_cast<const float4*>(bias + (size_t)n * DDIM + d);
#pragma unroll
    for (int i = 0; i < 8; ++i) {
        const int b = b0 + i;
        float4 o;
        o.x = acc[i][0].x + bv.x;
        o.y = acc[i][0].y + bv.y;
        o.z = acc[i][1].x + bv.z;
        o.w = acc[i][1].y + bv.w;
        *reinterpret_cast<float4*>(out + ((size_t)b * NPATCH + n) * DDIM + d) = o;
    }
}

extern "C" void kernel_launch(void* const* d_in, const int* in_sizes, int n_in,
                              void* d_out, int out_size, void* d_ws, size_t ws_size,
                              hipStream_t stream) {
    const float* x    = (const float*)d_in[0];
    const float* W    = (const float*)d_in[1];
    const float* bias = (const float*)d_in[2];
    float* out = (float*)d_out;
    float* P   = (float*)d_ws;   // 196*32*768*4 = 19.3 MB

    int total = NPATCH * BATCH * PDIM;
    extract_patches_kernel<<<(total + 255) / 256, 256, 0, stream>>>(x, P);
    patch_gemm_kernel<<<NPATCH * NDBLK, 256, 0, stream>>>(P, W, bias, out);
}